// Round 14
// baseline (121.245 us; speedup 1.0000x reference)
//
#include <hip/hip_runtime.h>

#define SEQ 2048
#define NH 16
#define DH 64
#define DMODEL 1024
#define NQKV 3072

typedef __attribute__((ext_vector_type(8))) short bf16x8;
typedef __attribute__((ext_vector_type(4))) short bf16x4;
typedef __attribute__((ext_vector_type(4))) float f32x4;

#define GLOAD16(src, dst)                                                              \
  __builtin_amdgcn_global_load_lds((const __attribute__((address_space(1))) void*)(src), \
                                   (__attribute__((address_space(3))) void*)(dst), 16, 0, 0)

#define EXP2(x) __builtin_amdgcn_exp2f(x)   // raw v_exp_f32: D = 2^S0

__device__ __forceinline__ unsigned short f2bf(float f) {
  union { float f; unsigned u; } v; v.f = f;
  unsigned r = v.u + 0x7FFFu + ((v.u >> 16) & 1u);
  return (unsigned short)(r >> 16);
}

__device__ __forceinline__ unsigned pkbf(float a, float b) {
  unsigned r;
  asm("v_cvt_pk_bf16_f32 %0, %1, %2" : "=v"(r) : "v"(a), "v"(b));
  return r;
}

// ---------------- fused prep: x->bf16, two weight transposes, rope tables ----------------
__device__ __forceinline__ void transw_body(const float* __restrict__ in,
                                            unsigned short* __restrict__ out,
                                            int K, int N, int k0, int n0, int tid,
                                            float (*Ts)[65]) {
#pragma unroll
  for (int p = 0; p < 4; ++p) {
    int id = p * 256 + tid;
    int r = id >> 4, c4 = (id & 15) * 4;
    const f32x4 v = *reinterpret_cast<const f32x4*>(&in[(size_t)(k0 + r) * N + n0 + c4]);
    Ts[r][c4] = v[0]; Ts[r][c4 + 1] = v[1]; Ts[r][c4 + 2] = v[2]; Ts[r][c4 + 3] = v[3];
  }
  __syncthreads();
#pragma unroll
  for (int p = 0; p < 2; ++p) {
    int id = p * 256 + tid;
    int n = id >> 3, k8 = (id & 7) * 8;
    unsigned short tmp[8];
#pragma unroll
    for (int i = 0; i < 8; ++i) tmp[i] = f2bf(Ts[k8 + i][n]);
    *reinterpret_cast<bf16x8*>(&out[(size_t)(n0 + n) * K + k0 + k8]) =
        *reinterpret_cast<bf16x8*>(tmp);
  }
}

__global__ __launch_bounds__(256) void prep_kernel(
    const float* __restrict__ x, const float* __restrict__ w_qkv,
    const float* __restrict__ w_out, unsigned short* __restrict__ Xb,
    unsigned short* __restrict__ WqkvT, unsigned short* __restrict__ WoutT,
    float* __restrict__ cost, float* __restrict__ sint) {
  __shared__ float Ts[64][65];
  const int tid = threadIdx.x;
  const int id = blockIdx.x;
  if (id < 2048) {
    int idx = id * 256 + tid;
    const f32x4 v0 = *reinterpret_cast<const f32x4*>(&x[(size_t)idx * 8]);
    const f32x4 v1 = *reinterpret_cast<const f32x4*>(&x[(size_t)idx * 8 + 4]);
    bf16x8 o;
    o[0] = (short)f2bf(v0[0]); o[1] = (short)f2bf(v0[1]);
    o[2] = (short)f2bf(v0[2]); o[3] = (short)f2bf(v0[3]);
    o[4] = (short)f2bf(v1[0]); o[5] = (short)f2bf(v1[1]);
    o[6] = (short)f2bf(v1[2]); o[7] = (short)f2bf(v1[3]);
    *reinterpret_cast<bf16x8*>(&Xb[(size_t)idx * 8]) = o;
  } else if (id < 2816) {
    int t = id - 2048;
    transw_body(w_qkv, WqkvT, DMODEL, NQKV, (t & 15) * 64, (t >> 4) * 64, tid, Ts);
  } else if (id < 3072) {
    int t = id - 2816;
    transw_body(w_out, WoutT, DMODEL, DMODEL, (t & 15) * 64, (t >> 4) * 64, tid, Ts);
  } else {
    int idx = (id - 3072) * 256 + tid;
    int t = idx >> 5, j = idx & 31;
    float inv = powf(10000.0f, -(float)(2 * j) / 64.0f);
    float a = (float)t * inv;
    cost[idx] = cosf(a);
    sint[idx] = sinf(a);
  }
}

// ---------------- QKV GEMM: BK=64, 48KB LDS (A single-buf + B dbuf) -> 3 blocks/CU ----------------
// 768 blocks = exactly 3/CU (removes the 1.5-wave tail of the 64KB version).
// Per K-tile: top vmcnt(0)+bar -> issue B(kb+1) [full-iter coverage] -> kh0 reads+MFMA ->
// kh1 reads -> lgkm(0)+bar -> issue A(kb+1) [covered by kh1 MFMA + 3-block TLP] -> kh1 MFMA.
__global__ __launch_bounds__(256) void gemm_qkv_kernel(
    const unsigned short* __restrict__ Xb, const unsigned short* __restrict__ BT,
    unsigned short* __restrict__ Qb, unsigned short* __restrict__ Kb,
    unsigned short* __restrict__ Vtg,
    const float* __restrict__ cost, const float* __restrict__ sint) {
  __shared__ unsigned short As[8192];      // [128 rows][64 k], 16B chunks ^ (row&7), single-buf
  __shared__ unsigned short Bs[2][8192];   // dbuf

  const int tid = threadIdx.x;
  const int lane = tid & 63;
  const int w = tid >> 6;
  const int lam = lane & 15;
  const int g = lane >> 4;
  const int wr = w >> 1, wc = w & 1;
  const int rowBase = blockIdx.x * 128;
  const int colBase = blockIdx.y * 128;

  f32x4 acc[4][4];
#pragma unroll
  for (int m = 0; m < 4; ++m)
#pragma unroll
    for (int n = 0; n < 4; ++n) acc[m][n] = (f32x4){0.f, 0.f, 0.f, 0.f};

#define STAGE_A(kk0)                                                                   \
  {                                                                                    \
    _Pragma("unroll") for (int c = 0; c < 4; ++c) {                                    \
      int ch = c * 256 + w * 64 + lane;                                                \
      int row = ch >> 3, q = ch & 7;                                                   \
      GLOAD16(Xb + (size_t)(rowBase + row) * DMODEL + (kk0) + ((q ^ (row & 7)) * 8),   \
              &As[0] + (c * 256 + w * 64) * 8);                                        \
    }                                                                                  \
  }
#define STAGE_B(buf, kk0)                                                              \
  {                                                                                    \
    _Pragma("unroll") for (int c = 0; c < 4; ++c) {                                    \
      int ch = c * 256 + w * 64 + lane;                                                \
      int row = ch >> 3, q = ch & 7;                                                   \
      GLOAD16(BT + (size_t)(colBase + row) * DMODEL + (kk0) + ((q ^ (row & 7)) * 8),   \
              &Bs[buf][0] + (c * 256 + w * 64) * 8);                                   \
    }                                                                                  \
  }

  STAGE_A(0);
  STAGE_B(0, 0);

  int cur = 0;
  for (int kb = 0; kb < 16; ++kb) {
    asm volatile("s_waitcnt vmcnt(0)" ::: "memory");   // A(kb) + B(kb) landed
    __builtin_amdgcn_s_barrier();

    if (kb + 1 < 16) STAGE_B(cur ^ 1, (kb + 1) * 64);  // covered by full iteration

    // ---- kh0 ----
    bf16x8 a[4], b[4];
#pragma unroll
    for (int m = 0; m < 4; ++m) {
      int row = wr * 64 + m * 16 + lam;
      a[m] = *reinterpret_cast<bf16x8*>(&As[row * 64 + ((g ^ (row & 7)) * 8)]);
    }
#pragma unroll
    for (int n = 0; n < 4; ++n) {
      int row = wc * 64 + n * 16 + lam;
      b[n] = *reinterpret_cast<bf16x8*>(&Bs[cur][row * 64 + ((g ^ (row & 7)) * 8)]);
    }
    __builtin_amdgcn_s_setprio(1);
#pragma unroll
    for (int m = 0; m < 4; ++m)
#pragma unroll
      for (int n = 0; n < 4; ++n)
        acc[m][n] = __builtin_amdgcn_mfma_f32_16x16x32_bf16(a[m], b[n], acc[m][n], 0, 0, 0);
    __builtin_amdgcn_s_setprio(0);

    // ---- kh1 reads ----
    bf16x8 a2[4], b2[4];
#pragma unroll
    for (int m = 0; m < 4; ++m) {
      int row = wr * 64 + m * 16 + lam;
      a2[m] = *reinterpret_cast<bf16x8*>(&As[row * 64 + (((4 + g) ^ (row & 7)) * 8)]);
    }
#pragma unroll
    for (int n = 0; n < 4; ++n) {
      int row = wc * 64 + n * 16 + lam;
      b2[n] = *reinterpret_cast<bf16x8*>(&Bs[cur][row * 64 + (((4 + g) ^ (row & 7)) * 8)]);
    }
    asm volatile("s_waitcnt lgkmcnt(0)" ::: "memory");  // all LDS reads of As/Bs[cur] done
    __builtin_amdgcn_s_barrier();

    if (kb + 1 < 16) STAGE_A((kb + 1) * 64);            // covered by kh1 MFMA + TLP

    __builtin_amdgcn_s_setprio(1);
#pragma unroll
    for (int m = 0; m < 4; ++m)
#pragma unroll
      for (int n = 0; n < 4; ++n)
        acc[m][n] = __builtin_amdgcn_mfma_f32_16x16x32_bf16(a2[m], b2[n], acc[m][n], 0, 0, 0);
    __builtin_amdgcn_s_setprio(0);
    cur ^= 1;
  }
#undef STAGE_A
#undef STAGE_B

  const int mat = blockIdx.y >> 3;   // 0=Q 1=K 2=V
  if (mat < 2) {
    unsigned short* dst = mat ? Kb : Qb;
    // fold attn scale AND log2(e) (exp2-domain softmax) into Q
    const float sc = mat ? 1.0f : 0.125f * 1.4426950408889634f;
    const int h = ((colBase & 1023) + wc * 64) >> 6;
#pragma unroll
    for (int m = 0; m < 4; ++m) {
#pragma unroll
      for (int r = 0; r < 4; ++r) {
        int row = rowBase + wr * 64 + m * 16 + g * 4 + r;
        int bi = row >> 11, t = row & 2047;
        unsigned short* out = &dst[(size_t)((bi * NH + h) * SEQ + t) * DH];
#pragma unroll
        for (int n = 0; n < 2; ++n) {
          int j = n * 16 + lam;
          float c = cost[t * 32 + j], s = sint[t * 32 + j];
          float x0 = acc[m][n][r], x1 = acc[m][n + 2][r];
          out[j] = f2bf((x0 * c - x1 * s) * sc);
          out[j + 32] = f2bf((x1 * c + x0 * s) * sc);
        }
      }
    }
  } else {
    unsigned short (*Vbuf)[44] = reinterpret_cast<unsigned short(*)[44]>(&As[0]);
    const int b = rowBase >> 11, t0 = rowBase & 2047;
#pragma unroll
    for (int cc = 0; cc < 4; ++cc) {
      __syncthreads();
      if (wc == (cc >> 1)) {
        const int n0 = (cc & 1) * 2;
#pragma unroll
        for (int m = 0; m < 4; ++m)
#pragma unroll
          for (int r = 0; r < 4; ++r)
#pragma unroll
            for (int n2 = 0; n2 < 2; ++n2)
              Vbuf[wr * 64 + m * 16 + g * 4 + r][n2 * 16 + lam] = f2bf(acc[m][n0 + n2][r]);
      }
      __syncthreads();
      const int colq0 = colBase - 2048 + cc * 32;
#pragma unroll
      for (int p2 = 0; p2 < 2; ++p2) {
        int ch = p2 * 256 + tid;
        int d = ch & 31, tq = (ch >> 5) * 8;
        unsigned short tmp[8];
#pragma unroll
        for (int i = 0; i < 8; ++i) tmp[i] = Vbuf[tq + i][d];
        int col = colq0 + d;
        int h = col >> 6, dd = col & 63;
        *reinterpret_cast<bf16x8*>(&Vtg[((size_t)(b * NH + h) * DH + dd) * SEQ + t0 + tq]) =
            *reinterpret_cast<bf16x8*>(tmp);
      }
    }
  }
}

// ---------------- causal flash attention: 128-kv tiles, swapped QK^T ----------------
// round-7 structure + exp2-domain softmax via raw v_exp_f32 + defer-max (T13).
__global__ __launch_bounds__(256) void attn_kernel(
    const unsigned short* __restrict__ Qb, const unsigned short* __restrict__ Kb,
    const unsigned short* __restrict__ Vtg, unsigned short* __restrict__ Ob) {
  __shared__ unsigned short Ks[2][8192];   // [buf][128 kv][64 d], chunk ^ (row&7)
  __shared__ unsigned short Vs[2][8192];   // [buf][64 d][128 kv], chunk ^ (row&15)
  __shared__ unsigned short Ps[4][2048];   // per-wave [16 q][128 kv], chunk ^ (lam&15)

  const int tid = threadIdx.x;
  const int lane = tid & 63;
  const int w = tid >> 6;
  const int lam = lane & 15;
  const int g = lane >> 4;
  const int bh = blockIdx.x;
  const int p = blockIdx.y;
  const int qtA = p, qtB = 31 - p;
  const int nA = (p >> 1) + 1;
  const int nB = ((31 - p) >> 1) + 1;
  const int nT = nA + nB;                  // 17
  const int ql = w * 16 + lam;

  const unsigned short* kallbase = Kb + (size_t)bh * SEQ * DH;
  const unsigned short* vallbase = Vtg + (size_t)bh * DH * SEQ;

  bf16x8 qb0, qb1;
  f32x4 oacc[4], sa0[4], sa1[4];
  float mr, lr;

#define LOADQ(qt)                                                                     \
  {                                                                                   \
    const unsigned short* qrow = Qb + ((size_t)bh * SEQ + (qt) * 64 + w * 16 + lam) * DH; \
    qb0 = *reinterpret_cast<const bf16x8*>(&qrow[g * 8]);                             \
    qb1 = *reinterpret_cast<const bf16x8*>(&qrow[g * 8 + 32]);                        \
  }
#define RESET_STATE()                                                                 \
  {                                                                                   \
    _Pragma("unroll") for (int f = 0; f < 4; ++f) oacc[f] = (f32x4){0.f, 0.f, 0.f, 0.f}; \
    mr = -1e30f; lr = 0.f;                                                            \
  }
#define STAGE(buf, jt)                                                                \
  {                                                                                   \
    const unsigned short* kb2 = kallbase + (size_t)(jt) * 128 * DH;                   \
    const unsigned short* vb2 = vallbase + (size_t)(jt) * 128;                        \
    _Pragma("unroll") for (int c = 0; c < 4; ++c) {                                   \
      int id = c * 256 + w * 64 + lane;                                               \
      int kr = id >> 3, kq = id & 7;                                                  \
      GLOAD16(kb2 + kr * DH + ((kq ^ (kr & 7)) * 8), &Ks[buf][0] + id * 8);           \
      int vr = id >> 4, vq = id & 15;                                                 \
      GLOAD16(vb2 + (size_t)vr * SEQ + ((vq ^ (vr & 15)) * 8), &Vs[buf][0] + id * 8); \
    }                                                                                 \
  }
#define FLUSHO(qt)                                                                    \
  {                                                                                   \
    const int b = bh >> 4, h = bh & 15;                                               \
    float rinv = 1.0f / lr;                                                           \
    _Pragma("unroll") for (int r = 0; r < 4; ++r) {                                   \
      int n = (qt) * 64 + w * 16 + g * 4 + r;                                         \
      float inv = __shfl(rinv, g * 4 + r);                                            \
      unsigned short* orow = &Ob[(size_t)(b * SEQ + n) * DMODEL + h * DH];            \
      _Pragma("unroll") for (int f = 0; f < 4; ++f) orow[f * 16 + lam] = f2bf(oacc[f][r] * inv); \
    }                                                                                 \
  }

  RESET_STATE();
  LOADQ(qtA);
  STAGE(0, 0);
  asm volatile("s_waitcnt vmcnt(0)" ::: "memory");
  __syncthreads();

  int cur = 0;
  for (int i = 0; i < nT; ++i) {
    const int onA = (i < nA);
    const int qt = onA ? qtA : qtB;
    const int j = onA ? i : (i - nA);

    if (i + 1 < nT) {
      const int jn = (i + 1 < nA) ? (i + 1) : (i + 1 - nA);
      STAGE(cur ^ 1, jn);
    }

    const int t1 = 2 * j + 1;
    const bool diag0 = (2 * j == qt);
    const bool diag1 = (t1 == qt);
    const bool skip1 = (t1 > qt);

#pragma unroll
    for (int f = 0; f < 4; ++f) {
      sa0[f] = (f32x4){0.f, 0.f, 0.f, 0.f};
      sa1[f] = (f32x4){0.f, 0.f, 0.f, 0.f};
    }
    __builtin_amdgcn_s_setprio(1);
#pragma unroll
    for (int f = 0; f < 4; ++f) {
      int kr = f * 16 + lam;
      bf16x8 k0 = *reinterpret_cast<bf16x8*>(&Ks[cur][kr * 64 + ((g ^ (kr & 7)) * 8)]);
      bf16x8 k1 = *reinterpret_cast<bf16x8*>(&Ks[cur][kr * 64 + (((g + 4) ^ (kr & 7)) * 8)]);
      sa0[f] = __builtin_amdgcn_mfma_f32_16x16x32_bf16(k0, qb0, sa0[f], 0, 0, 0);
      sa0[f] = __builtin_amdgcn_mfma_f32_16x16x32_bf16(k1, qb1, sa0[f], 0, 0, 0);
    }
    if (!skip1) {
#pragma unroll
      for (int f = 0; f < 4; ++f) {
        int kr = 64 + f * 16 + lam;
        bf16x8 k0 = *reinterpret_cast<bf16x8*>(&Ks[cur][kr * 64 + ((g ^ (kr & 7)) * 8)]);
        bf16x8 k1 = *reinterpret_cast<bf16x8*>(&Ks[cur][kr * 64 + (((g + 4) ^ (kr & 7)) * 8)]);
        sa1[f] = __builtin_amdgcn_mfma_f32_16x16x32_bf16(k0, qb0, sa1[f], 0, 0, 0);
        sa1[f] = __builtin_amdgcn_mfma_f32_16x16x32_bf16(k1, qb1, sa1[f], 0, 0, 0);
      }
    }
    __builtin_amdgcn_s_setprio(0);

    if (diag0) {
#pragma unroll
      for (int f = 0; f < 4; ++f)
#pragma unroll
        for (int r = 0; r < 4; ++r)
          if (f * 16 + g * 4 + r > ql) sa0[f][r] = -1e30f;
    }
    if (diag1) {
#pragma unroll
      for (int f = 0; f < 4; ++f)
#pragma unroll
        for (int r = 0; r < 4; ++r)
          if (f * 16 + g * 4 + r > ql) sa1[f][r] = -1e30f;
    }

    // ---- online softmax (exp2 domain; log2e pre-folded into Q; raw v_exp_f32) ----
    float mx = -1e30f;
#pragma unroll
    for (int f = 0; f < 4; ++f)
#pragma unroll
      for (int r = 0; r < 4; ++r) mx = fmaxf(mx, sa0[f][r]);
    if (!skip1) {
#pragma unroll
      for (int f = 0; f < 4; ++f)
#pragma unroll
        for (int r = 0; r < 4; ++r) mx = fmaxf(mx, sa1[f][r]);
    }
    mx = fmaxf(mx, __shfl_xor(mx, 16));
    mx = fmaxf(mx, __shfl_xor(mx, 32));

    // defer-max (T13): if max grew by <= 8 (log2), keep old m; P bounded by 2^8.
    float mn = mr, alpha = 1.0f;
    if (!__all(mx - mr <= 8.0f)) {
      mn = fmaxf(mr, mx);
      alpha = EXP2(mr - mn);
      mr = mn;
#pragma unroll
      for (int r = 0; r < 4; ++r) {
        float af = __shfl(alpha, g * 4 + r);
#pragma unroll
        for (int f = 0; f < 4; ++f) oacc[f][r] *= af;
      }
    }

    float sum = 0.f;
#pragma unroll
    for (int f = 0; f < 4; ++f)
#pragma unroll
      for (int r = 0; r < 4; ++r) {
        sa0[f][r] = EXP2(sa0[f][r] - mn);
        sum += sa0[f][r];
      }
    if (!skip1) {
#pragma unroll
      for (int f = 0; f < 4; ++f)
#pragma unroll
        for (int r = 0; r < 4; ++r) {
          sa1[f][r] = EXP2(sa1[f][r] - mn);
          sum += sa1[f][r];
        }
    }
    sum += __shfl_xor(sum, 16);
    sum += __shfl_xor(sum, 32);
    lr = lr * alpha + sum;

#pragma unroll
    for (int f = 0; f < 4; ++f) {
      uint2 u;
      u.x = pkbf(sa0[f][0], sa0[f][1]);
      u.y = pkbf(sa0[f][2], sa0[f][3]);
      int chunk = f * 2 + (g >> 1);
      *reinterpret_cast<uint2*>(
          &Ps[w][lam * 128 + ((chunk ^ (lam & 15)) * 8) + ((g & 1) * 4)]) = u;
    }
    if (!skip1) {
#pragma unroll
      for (int f = 0; f < 4; ++f) {
        uint2 u;
        u.x = pkbf(sa1[f][0], sa1[f][1]);
        u.y = pkbf(sa1[f][2], sa1[f][3]);
        int chunk = 8 + f * 2 + (g >> 1);
        *reinterpret_cast<uint2*>(
            &Ps[w][lam * 128 + ((chunk ^ (lam & 15)) * 8) + ((g & 1) * 4)]) = u;
      }
    }

    bf16x8 pa0 = *reinterpret_cast<bf16x8*>(&Ps[w][lam * 128 + ((g ^ (lam & 15)) * 8)]);
    bf16x8 pa1 = *reinterpret_cast<bf16x8*>(&Ps[w][lam * 128 + (((4 + g) ^ (lam & 15)) * 8)]);
    __builtin_amdgcn_s_setprio(1);
#pragma unroll
    for (int f = 0; f < 4; ++f) {
      int vr = f * 16 + lam;
      bf16x8 v0 = *reinterpret_cast<bf16x8*>(&Vs[cur][vr * 128 + ((g ^ (vr & 15)) * 8)]);
      bf16x8 v1 = *reinterpret_cast<bf16x8*>(&Vs[cur][vr * 128 + (((4 + g) ^ (vr & 15)) * 8)]);
      oacc[f] = __builtin_amdgcn_mfma_f32_16x16x32_bf16(pa0, v0, oacc[f], 0, 0, 0);
      oacc[f] = __builtin_amdgcn_mfma_f32_16x16x32_bf16(pa1, v1, oacc[f], 0, 0, 0);
    }
    __builtin_amdgcn_s_setprio(0);
    if (!skip1) {
      bf16x8 pa2 = *reinterpret_cast<bf16x8*>(&Ps[w][lam * 128 + (((8 + g) ^ (lam & 15)) * 8)]);
      bf16x8 pa3 = *reinterpret_cast<bf16x8*>(&Ps[w][lam * 128 + (((12 + g) ^ (lam & 15)) * 8)]);
      __builtin_amdgcn_s_setprio(1);
#pragma unroll
      for (int f = 0; f < 4; ++f) {
        int vr = f * 16 + lam;
        bf16x8 v2 = *reinterpret_cast<bf16x8*>(&Vs[cur][vr * 128 + (((8 + g) ^ (vr & 15)) * 8)]);
        bf16x8 v3 = *reinterpret_cast<bf16x8*>(&Vs[cur][vr * 128 + (((12 + g) ^ (vr & 15)) * 8)]);
        oacc[f] = __builtin_amdgcn_mfma_f32_16x16x32_bf16(pa2, v2, oacc[f], 0, 0, 0);
        oacc[f] = __builtin_amdgcn_mfma_f32_16x16x32_bf16(pa3, v3, oacc[f], 0, 0, 0);
      }
      __builtin_amdgcn_s_setprio(0);
    }

    if (i == nA - 1) {
      FLUSHO(qtA);
      RESET_STATE();
      LOADQ(qtB);
    }

    asm volatile("s_waitcnt vmcnt(0)" ::: "memory");
    __syncthreads();
    cur ^= 1;
  }
  FLUSHO(qtB);
#undef LOADQ
#undef RESET_STATE
#undef STAGE
#undef FLUSHO
}

// ------------- output GEMM: BK=64, 2-deep counted-vmcnt (round-7 proven) -------------
__global__ __launch_bounds__(256) void gemm_out_kernel(
    const unsigned short* __restrict__ A, const unsigned short* __restrict__ BT,
    float* __restrict__ C) {
  __shared__ unsigned short As[2][8192];
  __shared__ unsigned short Bs[2][8192];

  const int tid = threadIdx.x;
  const int lane = tid & 63;
  const int w = tid >> 6;
  const int lam = lane & 15;
  const int g = lane >> 4;
  const int wr = w >> 1, wc = w & 1;
  const int rowBase = blockIdx.x * 128;
  const int colBase = blockIdx.y * 128;

  f32x4 acc[4][4];
#pragma unroll
  for (int m = 0; m < 4; ++m)
#pragma unroll
    for (int n = 0; n < 4; ++n) acc[m][n] = (f32x4){0.f, 0.f, 0.f, 0.f};

#define GSTAGE(buf, kk0)                                                               \
  {                                                                                    \
    _Pragma("unroll") for (int c = 0; c < 4; ++c) {                                    \
      int ch = c * 256 + w * 64 + lane;                                                \
      int row = ch >> 3, q = ch & 7;                                                   \
      GLOAD16(A + (size_t)(rowBase + row) * DMODEL + (kk0) + ((q ^ (row & 7)) * 8),    \
              &As[buf][0] + (c * 256 + w * 64) * 8);                                   \
      GLOAD16(BT + (size_t)(colBase + row) * DMODEL + (kk0) + ((q ^ (row & 7)) * 8),   \
              &Bs[buf][0] + (c * 256 + w * 64) * 8);                                   \
    }                                                                                  \
  }

  GSTAGE(0, 0);

  for (int kb = 0; kb < 16; ++kb) {
    if (kb + 1 < 16) {
      GSTAGE((kb + 1) & 1, (kb + 1) * 64);
      asm volatile("s_waitcnt vmcnt(8)" ::: "memory");
    } else {
      asm volatile("s_waitcnt vmcnt(0)" ::: "memory");
    }
    __builtin_amdgcn_s_barrier();
    const int cb = kb & 1;
#pragma unroll
    for (int kh = 0; kh < 2; ++kh) {
      bf16x8 a[4], b[4];
#pragma unroll
      for (int m = 0; m < 4; ++m) {
        int row = wr * 64 + m * 16 + lam;
        a[m] = *reinterpret_cast<bf16x8*>(&As[cb][row * 64 + (((kh * 4 + g) ^ (row & 7)) * 8)]);
      }
#pragma unroll
      for (int n = 0; n < 4; ++n) {
        int row = wc * 64 + n * 16 + lam;
        b[n] = *reinterpret_cast<bf16x8*>(&Bs[cb][row * 64 + (((kh * 4 + g) ^ (row & 7)) * 8)]);
      }
      __builtin_amdgcn_s_setprio(1);
#pragma unroll
      for (int m = 0; m < 4; ++m)
#pragma unroll
        for (int n = 0; n < 4; ++n)
          acc[m][n] = __builtin_amdgcn_mfma_f32_16x16x32_bf16(a[m], b[n], acc[m][n], 0, 0, 0);
      __builtin_amdgcn_s_setprio(0);
    }
    asm volatile("s_waitcnt lgkmcnt(0)" ::: "memory");
    __builtin_amdgcn_s_barrier();
  }
#undef GSTAGE

#pragma unroll
  for (int m = 0; m < 4; ++m)
#pragma unroll
    for (int r = 0; r < 4; ++r) {
      int row = rowBase + wr * 64 + m * 16 + g * 4 + r;
#pragma unroll
      for (int n = 0; n < 4; ++n)
        C[(size_t)row * DMODEL + colBase + wc * 64 + n * 16 + lam] = acc[m][n][r];
    }
}

extern "C" void kernel_launch(void* const* d_in, const int* in_sizes, int n_in,
                              void* d_out, int out_size, void* d_ws, size_t ws_size,
                              hipStream_t stream) {
  const float* x = (const float*)d_in[0];       // [2][2048][1024]
  const float* w_qkv = (const float*)d_in[1];   // [1024][3072]
  const float* w_out = (const float*)d_in[2];   // [1024][1024]
  float* out = (float*)d_out;

  char* ws = (char*)d_ws;
  const size_t MB = 1024 * 1024;
  unsigned short* WqkvT = (unsigned short*)(ws);             // 6MB  [phase1]
  float* cost = (float*)(ws + 6 * MB);
  float* sint = cost + SEQ * 32;
  unsigned short* Ob = (unsigned short*)(ws);                // 8MB  [after gemm_qkv]
  unsigned short* WoutT = (unsigned short*)(ws + 8 * MB);    // 2MB
  unsigned short* Qb = (unsigned short*)(ws + 10 * MB);      // 8MB
  unsigned short* Kb = (unsigned short*)(ws + 18 * MB);      // 8MB
  unsigned short* Vtg = (unsigned short*)(ws + 26 * MB);     // 8MB   [bh][d][t]
  unsigned short* Xb = (unsigned short*)d_out;               // scratch; overwritten by gemm_out

  prep_kernel<<<3328, 256, 0, stream>>>(x, w_qkv, w_out, Xb, WqkvT, WoutT, cost, sint);
  gemm_qkv_kernel<<<dim3(32, 24), 256, 0, stream>>>(Xb, WqkvT, Qb, Kb, Vtg, cost, sint);
  attn_kernel<<<dim3(32, 16), 256, 0, stream>>>(Qb, Kb, Vtg, Ob);
  gemm_out_kernel<<<dim3(32, 8), 256, 0, stream>>>(Ob, WoutT, out);
}

// Round 15
// 115.814 us; speedup vs baseline: 1.0469x; 1.0469x over previous
//
#include <hip/hip_runtime.h>

#define SEQ 2048
#define NH 16
#define DH 64
#define DMODEL 1024
#define NQKV 3072

typedef __attribute__((ext_vector_type(8))) short bf16x8;
typedef __attribute__((ext_vector_type(4))) short bf16x4;
typedef __attribute__((ext_vector_type(4))) float f32x4;

#define GLOAD16(src, dst)                                                              \
  __builtin_amdgcn_global_load_lds((const __attribute__((address_space(1))) void*)(src), \
                                   (__attribute__((address_space(3))) void*)(dst), 16, 0, 0)

#define EXP2(x) __builtin_amdgcn_exp2f(x)   // raw v_exp_f32: D = 2^S0

__device__ __forceinline__ unsigned short f2bf(float f) {
  union { float f; unsigned u; } v; v.f = f;
  unsigned r = v.u + 0x7FFFu + ((v.u >> 16) & 1u);
  return (unsigned short)(r >> 16);
}

__device__ __forceinline__ unsigned pkbf(float a, float b) {
  unsigned r;
  asm("v_cvt_pk_bf16_f32 %0, %1, %2" : "=v"(r) : "v"(a), "v"(b));
  return r;
}

// ---------------- fused prep: x->bf16, two weight transposes, rope tables ----------------
__device__ __forceinline__ void transw_body(const float* __restrict__ in,
                                            unsigned short* __restrict__ out,
                                            int K, int N, int k0, int n0, int tid,
                                            float (*Ts)[65]) {
#pragma unroll
  for (int p = 0; p < 4; ++p) {
    int id = p * 256 + tid;
    int r = id >> 4, c4 = (id & 15) * 4;
    const f32x4 v = *reinterpret_cast<const f32x4*>(&in[(size_t)(k0 + r) * N + n0 + c4]);
    Ts[r][c4] = v[0]; Ts[r][c4 + 1] = v[1]; Ts[r][c4 + 2] = v[2]; Ts[r][c4 + 3] = v[3];
  }
  __syncthreads();
#pragma unroll
  for (int p = 0; p < 2; ++p) {
    int id = p * 256 + tid;
    int n = id >> 3, k8 = (id & 7) * 8;
    unsigned short tmp[8];
#pragma unroll
    for (int i = 0; i < 8; ++i) tmp[i] = f2bf(Ts[k8 + i][n]);
    *reinterpret_cast<bf16x8*>(&out[(size_t)(n0 + n) * K + k0 + k8]) =
        *reinterpret_cast<bf16x8*>(tmp);
  }
}

__global__ __launch_bounds__(256) void prep_kernel(
    const float* __restrict__ x, const float* __restrict__ w_qkv,
    const float* __restrict__ w_out, unsigned short* __restrict__ Xb,
    unsigned short* __restrict__ WqkvT, unsigned short* __restrict__ WoutT,
    float* __restrict__ cost, float* __restrict__ sint) {
  __shared__ float Ts[64][65];
  const int tid = threadIdx.x;
  const int id = blockIdx.x;
  if (id < 2048) {
    int idx = id * 256 + tid;
    const f32x4 v0 = *reinterpret_cast<const f32x4*>(&x[(size_t)idx * 8]);
    const f32x4 v1 = *reinterpret_cast<const f32x4*>(&x[(size_t)idx * 8 + 4]);
    bf16x8 o;
    o[0] = (short)f2bf(v0[0]); o[1] = (short)f2bf(v0[1]);
    o[2] = (short)f2bf(v0[2]); o[3] = (short)f2bf(v0[3]);
    o[4] = (short)f2bf(v1[0]); o[5] = (short)f2bf(v1[1]);
    o[6] = (short)f2bf(v1[2]); o[7] = (short)f2bf(v1[3]);
    *reinterpret_cast<bf16x8*>(&Xb[(size_t)idx * 8]) = o;
  } else if (id < 2816) {
    int t = id - 2048;
    transw_body(w_qkv, WqkvT, DMODEL, NQKV, (t & 15) * 64, (t >> 4) * 64, tid, Ts);
  } else if (id < 3072) {
    int t = id - 2816;
    transw_body(w_out, WoutT, DMODEL, DMODEL, (t & 15) * 64, (t >> 4) * 64, tid, Ts);
  } else {
    int idx = (id - 3072) * 256 + tid;
    int t = idx >> 5, j = idx & 31;
    float inv = powf(10000.0f, -(float)(2 * j) / 64.0f);
    float a = (float)t * inv;
    cost[idx] = cosf(a);
    sint[idx] = sinf(a);
  }
}

// ---------------- QKV GEMM: BK=64, 2-deep counted-vmcnt (round-7/13 proven, 47.5us) ----------------
__global__ __launch_bounds__(256) void gemm_qkv_kernel(
    const unsigned short* __restrict__ Xb, const unsigned short* __restrict__ BT,
    unsigned short* __restrict__ Qb, unsigned short* __restrict__ Kb,
    unsigned short* __restrict__ Vtg,
    const float* __restrict__ cost, const float* __restrict__ sint) {
  __shared__ unsigned short As[2][8192];   // [buf][128 rows][64 k], 16B chunks ^ (row&7)
  __shared__ unsigned short Bs[2][8192];

  const int tid = threadIdx.x;
  const int lane = tid & 63;
  const int w = tid >> 6;
  const int lam = lane & 15;
  const int g = lane >> 4;
  const int wr = w >> 1, wc = w & 1;
  const int rowBase = blockIdx.x * 128;
  const int colBase = blockIdx.y * 128;

  f32x4 acc[4][4];
#pragma unroll
  for (int m = 0; m < 4; ++m)
#pragma unroll
    for (int n = 0; n < 4; ++n) acc[m][n] = (f32x4){0.f, 0.f, 0.f, 0.f};

#define GSTAGE(buf, kk0)                                                               \
  {                                                                                    \
    _Pragma("unroll") for (int c = 0; c < 4; ++c) {                                    \
      int ch = c * 256 + w * 64 + lane;                                                \
      int row = ch >> 3, q = ch & 7;                                                   \
      GLOAD16(Xb + (size_t)(rowBase + row) * DMODEL + (kk0) + ((q ^ (row & 7)) * 8),   \
              &As[buf][0] + (c * 256 + w * 64) * 8);                                   \
      GLOAD16(BT + (size_t)(colBase + row) * DMODEL + (kk0) + ((q ^ (row & 7)) * 8),   \
              &Bs[buf][0] + (c * 256 + w * 64) * 8);                                   \
    }                                                                                  \
  }

  GSTAGE(0, 0);

  for (int kb = 0; kb < 16; ++kb) {
    if (kb + 1 < 16) {
      GSTAGE((kb + 1) & 1, (kb + 1) * 64);
      asm volatile("s_waitcnt vmcnt(8)" ::: "memory");   // current tile's 8 loads done
    } else {
      asm volatile("s_waitcnt vmcnt(0)" ::: "memory");
    }
    __builtin_amdgcn_s_barrier();
    const int cb = kb & 1;
#pragma unroll
    for (int kh = 0; kh < 2; ++kh) {
      bf16x8 a[4], b[4];
#pragma unroll
      for (int m = 0; m < 4; ++m) {
        int row = wr * 64 + m * 16 + lam;
        a[m] = *reinterpret_cast<bf16x8*>(&As[cb][row * 64 + (((kh * 4 + g) ^ (row & 7)) * 8)]);
      }
#pragma unroll
      for (int n = 0; n < 4; ++n) {
        int row = wc * 64 + n * 16 + lam;
        b[n] = *reinterpret_cast<bf16x8*>(&Bs[cb][row * 64 + (((kh * 4 + g) ^ (row & 7)) * 8)]);
      }
      __builtin_amdgcn_s_setprio(1);
#pragma unroll
      for (int m = 0; m < 4; ++m)
#pragma unroll
        for (int n = 0; n < 4; ++n)
          acc[m][n] = __builtin_amdgcn_mfma_f32_16x16x32_bf16(a[m], b[n], acc[m][n], 0, 0, 0);
      __builtin_amdgcn_s_setprio(0);
    }
    asm volatile("s_waitcnt lgkmcnt(0)" ::: "memory");
    __builtin_amdgcn_s_barrier();
  }
#undef GSTAGE

  const int mat = blockIdx.y >> 3;   // 0=Q 1=K 2=V
  if (mat < 2) {
    unsigned short* dst = mat ? Kb : Qb;
    // fold attn scale AND log2(e) (exp2-domain softmax) into Q
    const float sc = mat ? 1.0f : 0.125f * 1.4426950408889634f;
    const int h = ((colBase & 1023) + wc * 64) >> 6;
#pragma unroll
    for (int m = 0; m < 4; ++m) {
#pragma unroll
      for (int r = 0; r < 4; ++r) {
        int row = rowBase + wr * 64 + m * 16 + g * 4 + r;
        int bi = row >> 11, t = row & 2047;
        unsigned short* out = &dst[(size_t)((bi * NH + h) * SEQ + t) * DH];
#pragma unroll
        for (int n = 0; n < 2; ++n) {
          int j = n * 16 + lam;
          float c = cost[t * 32 + j], s = sint[t * 32 + j];
          float x0 = acc[m][n][r], x1 = acc[m][n + 2][r];
          out[j] = f2bf((x0 * c - x1 * s) * sc);
          out[j + 32] = f2bf((x1 * c + x0 * s) * sc);
        }
      }
    }
  } else {
    unsigned short (*Vbuf)[44] = reinterpret_cast<unsigned short(*)[44]>(&As[0][0]);
    const int b = rowBase >> 11, t0 = rowBase & 2047;
#pragma unroll
    for (int cc = 0; cc < 4; ++cc) {
      __syncthreads();
      if (wc == (cc >> 1)) {
        const int n0 = (cc & 1) * 2;
#pragma unroll
        for (int m = 0; m < 4; ++m)
#pragma unroll
          for (int r = 0; r < 4; ++r)
#pragma unroll
            for (int n2 = 0; n2 < 2; ++n2)
              Vbuf[wr * 64 + m * 16 + g * 4 + r][n2 * 16 + lam] = f2bf(acc[m][n0 + n2][r]);
      }
      __syncthreads();
      const int colq0 = colBase - 2048 + cc * 32;
#pragma unroll
      for (int p2 = 0; p2 < 2; ++p2) {
        int ch = p2 * 256 + tid;
        int d = ch & 31, tq = (ch >> 5) * 8;
        unsigned short tmp[8];
#pragma unroll
        for (int i = 0; i < 8; ++i) tmp[i] = Vbuf[tq + i][d];
        int col = colq0 + d;
        int h = col >> 6, dd = col & 63;
        *reinterpret_cast<bf16x8*>(&Vtg[((size_t)(b * NH + h) * DH + dd) * SEQ + t0 + tq]) =
            *reinterpret_cast<bf16x8*>(tmp);
      }
    }
  }
}

// ---------------- causal flash attention: 128-kv tiles, swapped QK^T ----------------
// round-7 structure + exp2-domain softmax via raw v_exp_f32 + defer-max (T13).
__global__ __launch_bounds__(256) void attn_kernel(
    const unsigned short* __restrict__ Qb, const unsigned short* __restrict__ Kb,
    const unsigned short* __restrict__ Vtg, unsigned short* __restrict__ Ob) {
  __shared__ unsigned short Ks[2][8192];   // [buf][128 kv][64 d], chunk ^ (row&7)
  __shared__ unsigned short Vs[2][8192];   // [buf][64 d][128 kv], chunk ^ (row&15)
  __shared__ unsigned short Ps[4][2048];   // per-wave [16 q][128 kv], chunk ^ (lam&15)

  const int tid = threadIdx.x;
  const int lane = tid & 63;
  const int w = tid >> 6;
  const int lam = lane & 15;
  const int g = lane >> 4;
  const int bh = blockIdx.x;
  const int p = blockIdx.y;
  const int qtA = p, qtB = 31 - p;
  const int nA = (p >> 1) + 1;
  const int nB = ((31 - p) >> 1) + 1;
  const int nT = nA + nB;                  // 17
  const int ql = w * 16 + lam;

  const unsigned short* kallbase = Kb + (size_t)bh * SEQ * DH;
  const unsigned short* vallbase = Vtg + (size_t)bh * DH * SEQ;

  bf16x8 qb0, qb1;
  f32x4 oacc[4], sa0[4], sa1[4];
  float mr, lr;

#define LOADQ(qt)                                                                     \
  {                                                                                   \
    const unsigned short* qrow = Qb + ((size_t)bh * SEQ + (qt) * 64 + w * 16 + lam) * DH; \
    qb0 = *reinterpret_cast<const bf16x8*>(&qrow[g * 8]);                             \
    qb1 = *reinterpret_cast<const bf16x8*>(&qrow[g * 8 + 32]);                        \
  }
#define RESET_STATE()                                                                 \
  {                                                                                   \
    _Pragma("unroll") for (int f = 0; f < 4; ++f) oacc[f] = (f32x4){0.f, 0.f, 0.f, 0.f}; \
    mr = -1e30f; lr = 0.f;                                                            \
  }
#define STAGE(buf, jt)                                                                \
  {                                                                                   \
    const unsigned short* kb2 = kallbase + (size_t)(jt) * 128 * DH;                   \
    const unsigned short* vb2 = vallbase + (size_t)(jt) * 128;                        \
    _Pragma("unroll") for (int c = 0; c < 4; ++c) {                                   \
      int id = c * 256 + w * 64 + lane;                                               \
      int kr = id >> 3, kq = id & 7;                                                  \
      GLOAD16(kb2 + kr * DH + ((kq ^ (kr & 7)) * 8), &Ks[buf][0] + id * 8);           \
      int vr = id >> 4, vq = id & 15;                                                 \
      GLOAD16(vb2 + (size_t)vr * SEQ + ((vq ^ (vr & 15)) * 8), &Vs[buf][0] + id * 8); \
    }                                                                                 \
  }
#define FLUSHO(qt)                                                                    \
  {                                                                                   \
    const int b = bh >> 4, h = bh & 15;                                               \
    float rinv = 1.0f / lr;                                                           \
    _Pragma("unroll") for (int r = 0; r < 4; ++r) {                                   \
      int n = (qt) * 64 + w * 16 + g * 4 + r;                                         \
      float inv = __shfl(rinv, g * 4 + r);                                            \
      unsigned short* orow = &Ob[(size_t)(b * SEQ + n) * DMODEL + h * DH];            \
      _Pragma("unroll") for (int f = 0; f < 4; ++f) orow[f * 16 + lam] = f2bf(oacc[f][r] * inv); \
    }                                                                                 \
  }

  RESET_STATE();
  LOADQ(qtA);
  STAGE(0, 0);
  asm volatile("s_waitcnt vmcnt(0)" ::: "memory");
  __syncthreads();

  int cur = 0;
  for (int i = 0; i < nT; ++i) {
    const int onA = (i < nA);
    const int qt = onA ? qtA : qtB;
    const int j = onA ? i : (i - nA);

    if (i + 1 < nT) {
      const int jn = (i + 1 < nA) ? (i + 1) : (i + 1 - nA);
      STAGE(cur ^ 1, jn);
    }

    const int t1 = 2 * j + 1;
    const bool diag0 = (2 * j == qt);
    const bool diag1 = (t1 == qt);
    const bool skip1 = (t1 > qt);

#pragma unroll
    for (int f = 0; f < 4; ++f) {
      sa0[f] = (f32x4){0.f, 0.f, 0.f, 0.f};
      sa1[f] = (f32x4){0.f, 0.f, 0.f, 0.f};
    }
    __builtin_amdgcn_s_setprio(1);
#pragma unroll
    for (int f = 0; f < 4; ++f) {
      int kr = f * 16 + lam;
      bf16x8 k0 = *reinterpret_cast<bf16x8*>(&Ks[cur][kr * 64 + ((g ^ (kr & 7)) * 8)]);
      bf16x8 k1 = *reinterpret_cast<bf16x8*>(&Ks[cur][kr * 64 + (((g + 4) ^ (kr & 7)) * 8)]);
      sa0[f] = __builtin_amdgcn_mfma_f32_16x16x32_bf16(k0, qb0, sa0[f], 0, 0, 0);
      sa0[f] = __builtin_amdgcn_mfma_f32_16x16x32_bf16(k1, qb1, sa0[f], 0, 0, 0);
    }
    if (!skip1) {
#pragma unroll
      for (int f = 0; f < 4; ++f) {
        int kr = 64 + f * 16 + lam;
        bf16x8 k0 = *reinterpret_cast<bf16x8*>(&Ks[cur][kr * 64 + ((g ^ (kr & 7)) * 8)]);
        bf16x8 k1 = *reinterpret_cast<bf16x8*>(&Ks[cur][kr * 64 + (((g + 4) ^ (kr & 7)) * 8)]);
        sa1[f] = __builtin_amdgcn_mfma_f32_16x16x32_bf16(k0, qb0, sa1[f], 0, 0, 0);
        sa1[f] = __builtin_amdgcn_mfma_f32_16x16x32_bf16(k1, qb1, sa1[f], 0, 0, 0);
      }
    }
    __builtin_amdgcn_s_setprio(0);

    if (diag0) {
#pragma unroll
      for (int f = 0; f < 4; ++f)
#pragma unroll
        for (int r = 0; r < 4; ++r)
          if (f * 16 + g * 4 + r > ql) sa0[f][r] = -1e30f;
    }
    if (diag1) {
#pragma unroll
      for (int f = 0; f < 4; ++f)
#pragma unroll
        for (int r = 0; r < 4; ++r)
          if (f * 16 + g * 4 + r > ql) sa1[f][r] = -1e30f;
    }

    // ---- online softmax (exp2 domain; log2e pre-folded into Q; raw v_exp_f32) ----
    float mx = -1e30f;
#pragma unroll
    for (int f = 0; f < 4; ++f)
#pragma unroll
      for (int r = 0; r < 4; ++r) mx = fmaxf(mx, sa0[f][r]);
    if (!skip1) {
#pragma unroll
      for (int f = 0; f < 4; ++f)
#pragma unroll
        for (int r = 0; r < 4; ++r) mx = fmaxf(mx, sa1[f][r]);
    }
    mx = fmaxf(mx, __shfl_xor(mx, 16));
    mx = fmaxf(mx, __shfl_xor(mx, 32));

    // defer-max (T13): if max grew by <= 8 (log2), keep old m; P bounded by 2^8.
    float mn = mr, alpha = 1.0f;
    if (!__all(mx - mr <= 8.0f)) {
      mn = fmaxf(mr, mx);
      alpha = EXP2(mr - mn);
      mr = mn;
#pragma unroll
      for (int r = 0; r < 4; ++r) {
        float af = __shfl(alpha, g * 4 + r);
#pragma unroll
        for (int f = 0; f < 4; ++f) oacc[f][r] *= af;
      }
    }

    float sum = 0.f;
#pragma unroll
    for (int f = 0; f < 4; ++f)
#pragma unroll
      for (int r = 0; r < 4; ++r) {
        sa0[f][r] = EXP2(sa0[f][r] - mn);
        sum += sa0[f][r];
      }
    if (!skip1) {
#pragma unroll
      for (int f = 0; f < 4; ++f)
#pragma unroll
        for (int r = 0; r < 4; ++r) {
          sa1[f][r] = EXP2(sa1[f][r] - mn);
          sum += sa1[f][r];
        }
    }
    sum += __shfl_xor(sum, 16);
    sum += __shfl_xor(sum, 32);
    lr = lr * alpha + sum;

#pragma unroll
    for (int f = 0; f < 4; ++f) {
      uint2 u;
      u.x = pkbf(sa0[f][0], sa0[f][1]);
      u.y = pkbf(sa0[f][2], sa0[f][3]);
      int chunk = f * 2 + (g >> 1);
      *reinterpret_cast<uint2*>(
          &Ps[w][lam * 128 + ((chunk ^ (lam & 15)) * 8) + ((g & 1) * 4)]) = u;
    }
    if (!skip1) {
#pragma unroll
      for (int f = 0; f < 4; ++f) {
        uint2 u;
        u.x = pkbf(sa1[f][0], sa1[f][1]);
        u.y = pkbf(sa1[f][2], sa1[f][3]);
        int chunk = 8 + f * 2 + (g >> 1);
        *reinterpret_cast<uint2*>(
            &Ps[w][lam * 128 + ((chunk ^ (lam & 15)) * 8) + ((g & 1) * 4)]) = u;
      }
    }

    bf16x8 pa0 = *reinterpret_cast<bf16x8*>(&Ps[w][lam * 128 + ((g ^ (lam & 15)) * 8)]);
    bf16x8 pa1 = *reinterpret_cast<bf16x8*>(&Ps[w][lam * 128 + (((4 + g) ^ (lam & 15)) * 8)]);
    __builtin_amdgcn_s_setprio(1);
#pragma unroll
    for (int f = 0; f < 4; ++f) {
      int vr = f * 16 + lam;
      bf16x8 v0 = *reinterpret_cast<bf16x8*>(&Vs[cur][vr * 128 + ((g ^ (vr & 15)) * 8)]);
      bf16x8 v1 = *reinterpret_cast<bf16x8*>(&Vs[cur][vr * 128 + (((4 + g) ^ (vr & 15)) * 8)]);
      oacc[f] = __builtin_amdgcn_mfma_f32_16x16x32_bf16(pa0, v0, oacc[f], 0, 0, 0);
      oacc[f] = __builtin_amdgcn_mfma_f32_16x16x32_bf16(pa1, v1, oacc[f], 0, 0, 0);
    }
    __builtin_amdgcn_s_setprio(0);
    if (!skip1) {
      bf16x8 pa2 = *reinterpret_cast<bf16x8*>(&Ps[w][lam * 128 + (((8 + g) ^ (lam & 15)) * 8)]);
      bf16x8 pa3 = *reinterpret_cast<bf16x8*>(&Ps[w][lam * 128 + (((12 + g) ^ (lam & 15)) * 8)]);
      __builtin_amdgcn_s_setprio(1);
#pragma unroll
      for (int f = 0; f < 4; ++f) {
        int vr = f * 16 + lam;
        bf16x8 v2 = *reinterpret_cast<bf16x8*>(&Vs[cur][vr * 128 + (((8 + g) ^ (vr & 15)) * 8)]);
        bf16x8 v3 = *reinterpret_cast<bf16x8*>(&Vs[cur][vr * 128 + (((12 + g) ^ (vr & 15)) * 8)]);
        oacc[f] = __builtin_amdgcn_mfma_f32_16x16x32_bf16(pa2, v2, oacc[f], 0, 0, 0);
        oacc[f] = __builtin_amdgcn_mfma_f32_16x16x32_bf16(pa3, v3, oacc[f], 0, 0, 0);
      }
      __builtin_amdgcn_s_setprio(0);
    }

    if (i == nA - 1) {
      FLUSHO(qtA);
      RESET_STATE();
      LOADQ(qtB);
    }

    asm volatile("s_waitcnt vmcnt(0)" ::: "memory");
    __syncthreads();
    cur ^= 1;
  }
  FLUSHO(qtB);
#undef LOADQ
#undef RESET_STATE
#undef STAGE
#undef FLUSHO
}

// ------------- output GEMM: BK=64, 2-deep counted-vmcnt (round-7 proven) -------------
__global__ __launch_bounds__(256) void gemm_out_kernel(
    const unsigned short* __restrict__ A, const unsigned short* __restrict__ BT,
    float* __restrict__ C) {
  __shared__ unsigned short As[2][8192];
  __shared__ unsigned short Bs[2][8192];

  const int tid = threadIdx.x;
  const int lane = tid & 63;
  const int w = tid >> 6;
  const int lam = lane & 15;
  const int g = lane >> 4;
  const int wr = w >> 1, wc = w & 1;
  const int rowBase = blockIdx.x * 128;
  const int colBase = blockIdx.y * 128;

  f32x4 acc[4][4];
#pragma unroll
  for (int m = 0; m < 4; ++m)
#pragma unroll
    for (int n = 0; n < 4; ++n) acc[m][n] = (f32x4){0.f, 0.f, 0.f, 0.f};

#define GSTAGE(buf, kk0)                                                               \
  {                                                                                    \
    _Pragma("unroll") for (int c = 0; c < 4; ++c) {                                    \
      int ch = c * 256 + w * 64 + lane;                                                \
      int row = ch >> 3, q = ch & 7;                                                   \
      GLOAD16(A + (size_t)(rowBase + row) * DMODEL + (kk0) + ((q ^ (row & 7)) * 8),    \
              &As[buf][0] + (c * 256 + w * 64) * 8);                                   \
      GLOAD16(BT + (size_t)(colBase + row) * DMODEL + (kk0) + ((q ^ (row & 7)) * 8),   \
              &Bs[buf][0] + (c * 256 + w * 64) * 8);                                   \
    }                                                                                  \
  }

  GSTAGE(0, 0);

  for (int kb = 0; kb < 16; ++kb) {
    if (kb + 1 < 16) {
      GSTAGE((kb + 1) & 1, (kb + 1) * 64);
      asm volatile("s_waitcnt vmcnt(8)" ::: "memory");
    } else {
      asm volatile("s_waitcnt vmcnt(0)" ::: "memory");
    }
    __builtin_amdgcn_s_barrier();
    const int cb = kb & 1;
#pragma unroll
    for (int kh = 0; kh < 2; ++kh) {
      bf16x8 a[4], b[4];
#pragma unroll
      for (int m = 0; m < 4; ++m) {
        int row = wr * 64 + m * 16 + lam;
        a[m] = *reinterpret_cast<bf16x8*>(&As[cb][row * 64 + (((kh * 4 + g) ^ (row & 7)) * 8)]);
      }
#pragma unroll
      for (int n = 0; n < 4; ++n) {
        int row = wc * 64 + n * 16 + lam;
        b[n] = *reinterpret_cast<bf16x8*>(&Bs[cb][row * 64 + (((kh * 4 + g) ^ (row & 7)) * 8)]);
      }
      __builtin_amdgcn_s_setprio(1);
#pragma unroll
      for (int m = 0; m < 4; ++m)
#pragma unroll
        for (int n = 0; n < 4; ++n)
          acc[m][n] = __builtin_amdgcn_mfma_f32_16x16x32_bf16(a[m], b[n], acc[m][n], 0, 0, 0);
      __builtin_amdgcn_s_setprio(0);
    }
    asm volatile("s_waitcnt lgkmcnt(0)" ::: "memory");
    __builtin_amdgcn_s_barrier();
  }
#undef GSTAGE

#pragma unroll
  for (int m = 0; m < 4; ++m)
#pragma unroll
    for (int r = 0; r < 4; ++r) {
      int row = rowBase + wr * 64 + m * 16 + g * 4 + r;
#pragma unroll
      for (int n = 0; n < 4; ++n)
        C[(size_t)row * DMODEL + colBase + wc * 64 + n * 16 + lam] = acc[m][n][r];
    }
}

extern "C" void kernel_launch(void* const* d_in, const int* in_sizes, int n_in,
                              void* d_out, int out_size, void* d_ws, size_t ws_size,
                              hipStream_t stream) {
  const float* x = (const float*)d_in[0];       // [2][2048][1024]
  const float* w_qkv = (const float*)d_in[1];   // [1024][3072]
  const float* w_out = (const float*)d_in[2];   // [1024][1024]
  float* out = (float*)d_out;

  char* ws = (char*)d_ws;
  const size_t MB = 1024 * 1024;
  unsigned short* WqkvT = (unsigned short*)(ws);             // 6MB  [phase1]
  float* cost = (float*)(ws + 6 * MB);
  float* sint = cost + SEQ * 32;
  unsigned short* Ob = (unsigned short*)(ws);                // 8MB  [after gemm_qkv]
  unsigned short* WoutT = (unsigned short*)(ws + 8 * MB);    // 2MB
  unsigned short* Qb = (unsigned short*)(ws + 10 * MB);      // 8MB
  unsigned short* Kb = (unsigned short*)(ws + 18 * MB);      // 8MB
  unsigned short* Vtg = (unsigned short*)(ws + 26 * MB);     // 8MB   [bh][d][t]
  unsigned short* Xb = (unsigned short*)d_out;               // scratch; overwritten by gemm_out

  prep_kernel<<<3328, 256, 0, stream>>>(x, w_qkv, w_out, Xb, WqkvT, WoutT, cost, sint);
  gemm_qkv_kernel<<<dim3(32, 24), 256, 0, stream>>>(Xb, WqkvT, Qb, Kb, Vtg, cost, sint);
  attn_kernel<<<dim3(32, 16), 256, 0, stream>>>(Qb, Kb, Vtg, Ob);
  gemm_out_kernel<<<dim3(32, 8), 256, 0, stream>>>(Ob, WoutT, out);
}